// Round 1
// baseline (1390.092 us; speedup 1.0000x reference)
//
#include <hip/hip_runtime.h>

#define NB 512      // boxes
#define NC 151      // classes
#define KDIM 4096
#define ROWS_PER_BLK 4

// ---------------- GEMM: out[r,c] = dot(A[r,:], W[:,c]) + bias[c] ----------------
// 128 blocks x 192 threads; 4 rows per block. A-row indices are block-uniform
// (scalar loads); W reads are coalesced across threads (consecutive c).
__global__ __launch_bounds__(192) void gemm_kernel(
    const float* __restrict__ A, const float* __restrict__ W,
    const float* __restrict__ bias, float* __restrict__ out)
{
  int c = threadIdx.x;
  int r0 = blockIdx.x * ROWS_PER_BLK;
  if (c >= NC) return;
  const float* a = A + (size_t)r0 * KDIM;
  const float* wp = W + c;
  float acc0 = 0.f, acc1 = 0.f, acc2 = 0.f, acc3 = 0.f;
#pragma unroll 8
  for (int k = 0; k < KDIM; ++k) {
    float w = wp[(size_t)k * NC];
    acc0 = fmaf(a[k],            w, acc0);
    acc1 = fmaf(a[k +   KDIM],   w, acc1);
    acc2 = fmaf(a[k + 2*KDIM],   w, acc2);
    acc3 = fmaf(a[k + 3*KDIM],   w, acc3);
  }
  float bb = bias[c];
  out[(size_t)(r0+0)*NC + c] = acc0 + bb;
  out[(size_t)(r0+1)*NC + c] = acc1 + bb;
  out[(size_t)(r0+2)*NC + c] = acc2 + bb;
  out[(size_t)(r0+3)*NC + c] = acc3 + bb;
}

// ---------------- Sequential greedy NMS decode ----------------
// One workgroup, 512 threads; thread j owns score row j (in ws global memory)
// and keeps (rowmax, argcls) in registers. Per iteration:
//   write (rowmax, flatidx) to LDS -> barrier -> wave0 reduces (max val,
//   min flat idx on ties) -> barrier -> all threads do overlap suppression.
__global__ __launch_bounds__(512) void decode_kernel(
    const float* __restrict__ obj_dists, const float* __restrict__ boxes,
    float* __restrict__ scores, float* __restrict__ commits)
{
#pragma clang fp contract(off)
  __shared__ float redval[NB];
  __shared__ int   redidx[NB];
  __shared__ int   selidx;
  const int j = threadIdx.x;

  // ---- phase A: softmax row j (full 151 classes), then zero background ----
  const float* xr = obj_dists + (size_t)j * NC;
  float* sr = scores + (size_t)j * NC;
  float m = xr[0];
  for (int c = 1; c < NC; ++c) m = fmaxf(m, xr[c]);
  float s = 0.f;
  for (int c = 0; c < NC; ++c) { float e = expf(xr[c] - m); s += e; sr[c] = e; }
  float rowmax = -3.4e38f; int argcls = 0;
  for (int c = 0; c < NC; ++c) {
    float v = (c == 0) ? 0.0f : (sr[c] / s);   // background zeroed
    sr[c] = v;
    if (v > rowmax) { rowmax = v; argcls = c; }  // first occurrence on ties
  }
  commits[j] = 0.0f;  // reference inits commits to zeros
  __syncthreads();

  for (int it = 0; it < NB; ++it) {
    redval[j] = rowmax;
    redidx[j] = j * NC + argcls;
    __syncthreads();
    if (j < 64) {
      float bv = redval[j]; int bi = redidx[j];
#pragma unroll
      for (int t = 1; t < 8; ++t) {
        float v = redval[j + 64*t]; int ix = redidx[j + 64*t];
        if (v > bv || (v == bv && ix < bi)) { bv = v; bi = ix; }
      }
      for (int off = 32; off > 0; off >>= 1) {
        float v = __shfl_down(bv, off);
        int   ix = __shfl_down(bi, off);
        if (v > bv || (v == bv && ix < bi)) { bv = v; bi = ix; }
      }
      if (j == 0) selidx = bi;
    }
    __syncthreads();
    const int bi   = selidx;
    const int bbox = bi / NC;
    const int bcls = bi - bbox * NC;

    if (j == bbox) {
      // commit, then retire the whole row (reference sets row to -1 AFTER the
      // column update; self-overlap zero is then overwritten -> net all -1).
      commits[j] = (float)bcls;
      for (int c = 0; c < NC; ++c) sr[c] = -1.0f;
      rowmax = -1.0f; argcls = 0;
    } else {
      const float* cb = boxes + (size_t)bi * 4;                 // committed box, class bcls
      const float* ob = boxes + ((size_t)j * NC + bcls) * 4;    // my box, class bcls
      float cx1 = cb[0], cy1 = cb[1], cx2 = cb[2], cy2 = cb[3];
      float x1  = ob[0], y1  = ob[1], x2  = ob[2], y2  = ob[3];
      float areaC = (cx2 - cx1 + 1.0f) * (cy2 - cy1 + 1.0f);
      float areaJ = (x2  - x1  + 1.0f) * (y2  - y1  + 1.0f);
      float iw = fminf(cx2, x2) - fmaxf(cx1, x1) + 1.0f;
      float ih = fminf(cy2, y2) - fmaxf(cy1, y1) + 1.0f;
      iw = fmaxf(iw, 0.0f); ih = fmaxf(ih, 0.0f);
      float inter = iw * ih;
      float uni = areaC + areaJ - inter;
      if (inter / uni >= 0.3f) {
        sr[bcls] = 0.0f;
        if (rowmax < 0.0f) {
          // retired row: entry resurrected from -1 to 0 (reference semantics)
          rowmax = 0.0f; argcls = bcls;
        } else if (rowmax == 0.0f) {
          if (bcls < argcls) argcls = bcls;
        } else if (argcls == bcls) {
          // my current max class was just suppressed: rescan the row
          float mm = -3.4e38f; int am = 0;
          for (int c = 0; c < NC; ++c) {
            float v = (c == bcls) ? 0.0f : sr[c];
            if (v > mm) { mm = v; am = c; }
          }
          rowmax = mm; argcls = am;
        }
      }
    }
    // next-iteration redval write is ordered by the barrier at loop top
  }
}

extern "C" void kernel_launch(void* const* d_in, const int* in_sizes, int n_in,
                              void* d_out, int out_size, void* d_ws, size_t ws_size,
                              hipStream_t stream) {
  const float* A     = (const float*)d_in[0];   // obj_fmap [512,4096]
  const float* boxes = (const float*)d_in[1];   // boxes_per_cls [512,151,4]
  const float* W     = (const float*)d_in[2];   // [4096,151]
  const float* bias  = (const float*)d_in[3];   // [151]
  float* out    = (float*)d_out;                // [512*151] obj_dists ++ [512] commits
  float* scores = (float*)d_ws;                 // [512*151] fp32 scratch

  gemm_kernel<<<NB / ROWS_PER_BLK, 192, 0, stream>>>(A, W, bias, out);
  decode_kernel<<<1, NB, 0, stream>>>(out, boxes, scores, out + NB * NC);
}

// Round 2
// 706.689 us; speedup vs baseline: 1.9670x; 1.9670x over previous
//
#include <hip/hip_runtime.h>
#include <limits.h>

#pragma clang fp contract(off)

#define NB 512
#define NC 151
#define KDIM 4096
#define KS 8
#define KCH (KDIM/KS)   // 512
#define NMS_TH 0.3f

typedef unsigned long long ull;

// ---- packed sort key: (orderable float << 32) | (0xFFFFFFFF - flatidx) ----
// max key == max value, ties -> min flat idx. Keys unique (flatidx unique).
__device__ __forceinline__ ull packkey(float v, int flatidx){
  unsigned u = __float_as_uint(v);
  u ^= (u & 0x80000000u) ? 0xFFFFFFFFu : 0x80000000u;
  return ((ull)u << 32) | (unsigned)(0xFFFFFFFFu - (unsigned)flatidx);
}
__device__ __forceinline__ int key_idx(ull k){ return (int)(0xFFFFFFFFu - (unsigned)(k & 0xFFFFFFFFu)); }
__device__ __forceinline__ bool key_pos(ull k){ return (unsigned)(k >> 32) > 0x80000000u; } // value > 0

// exact same IoU arithmetic/order as the reference (fp contract off file-wide)
__device__ __forceinline__ bool overlap_ge(const float4& c, const float4& o){
  float areaC = (c.z - c.x + 1.0f) * (c.w - c.y + 1.0f);
  float areaJ = (o.z - o.x + 1.0f) * (o.w - o.y + 1.0f);
  float iw = fminf(c.z, o.z) - fmaxf(c.x, o.x) + 1.0f;
  float ih = fminf(c.w, o.w) - fmaxf(c.y, o.y) + 1.0f;
  iw = fmaxf(iw, 0.0f); ih = fmaxf(ih, 0.0f);
  float inter = iw * ih;
  float uni = areaC + areaJ - inter;
  return inter / uni >= NMS_TH;
}

__device__ __forceinline__ bool mbit(const unsigned m[5], int c){
  bool r = false;
#pragma unroll
  for (int k = 0; k < 5; ++k) r = (k == (c >> 5)) ? (((m[k] >> (c & 31)) & 1u) != 0) : r;
  return r;
}

// ---------------- GEMM: split-K partials ----------------
__global__ __launch_bounds__(192) void gemm_partial(
    const float* __restrict__ A, const float* __restrict__ W, float* __restrict__ part)
{
  __shared__ float sA[4 * KCH];  // 8 KB
  int rb = blockIdx.x, ks = blockIdx.y;
  for (int i = threadIdx.x; i < 4 * (KCH / 4); i += 192) {
    int r = i >> 7;          // KCH/4 = 128 float4 per row
    int k4 = i & 127;
    float4 v = *(const float4*)(A + (size_t)(rb * 4 + r) * KDIM + ks * KCH + k4 * 4);
    *(float4*)(sA + r * KCH + k4 * 4) = v;
  }
  __syncthreads();
  int c = threadIdx.x;
  if (c < NC) {
    const float* wp = W + (size_t)ks * KCH * NC + c;
    float a0 = 0.f, a1 = 0.f, a2 = 0.f, a3 = 0.f;
#pragma unroll 8
    for (int k = 0; k < KCH; ++k) {
      float w = wp[(size_t)k * NC];
      a0 = fmaf(sA[k],           w, a0);
      a1 = fmaf(sA[KCH + k],     w, a1);
      a2 = fmaf(sA[2 * KCH + k], w, a2);
      a3 = fmaf(sA[3 * KCH + k], w, a3);
    }
    float* o = part + (size_t)ks * NB * NC + (size_t)rb * 4 * NC + c;
    o[0] = a0; o[NC] = a1; o[2 * NC] = a2; o[3 * NC] = a3;
  }
}

__global__ void gemm_reduce(const float* __restrict__ part, const float* __restrict__ bias,
                            float* __restrict__ out){
  int i = blockIdx.x * 256 + threadIdx.x;
  if (i >= NB * NC) return;
  float acc = 0.f;
#pragma unroll
  for (int ks = 0; ks < KS; ++ks) acc += part[(size_t)ks * NB * NC + i];
  out[i] = acc + bias[i - (i / NC) * NC];
}

// fallback (ws too small): round-1 single-kernel gemm
__global__ __launch_bounds__(192) void gemm_full(
    const float* __restrict__ A, const float* __restrict__ W,
    const float* __restrict__ bias, float* __restrict__ out)
{
  int c = threadIdx.x;
  int r0 = blockIdx.x * 4;
  if (c >= NC) return;
  const float* a = A + (size_t)r0 * KDIM;
  const float* wp = W + c;
  float a0 = 0.f, a1 = 0.f, a2 = 0.f, a3 = 0.f;
#pragma unroll 8
  for (int k = 0; k < KDIM; ++k) {
    float w = wp[(size_t)k * NC];
    a0 = fmaf(a[k],            w, a0);
    a1 = fmaf(a[k + KDIM],     w, a1);
    a2 = fmaf(a[k + 2 * KDIM], w, a2);
    a3 = fmaf(a[k + 3 * KDIM], w, a3);
  }
  float bb = bias[c];
  out[(size_t)(r0 + 0) * NC + c] = a0 + bb;
  out[(size_t)(r0 + 1) * NC + c] = a1 + bb;
  out[(size_t)(r0 + 2) * NC + c] = a2 + bb;
  out[(size_t)(r0 + 3) * NC + c] = a3 + bb;
}

// ---------------- Multi-commit greedy NMS decode ----------------
// One block, 512 threads; thread j owns row j. Per round: top-8 global
// candidates (exact, packed-u64 butterfly), chain-validity prefix, commit p.
__global__ __launch_bounds__(512) void decode_kernel(
    const float* __restrict__ obj_dists, const float* __restrict__ boxes,
    float* __restrict__ commits)
{
  __shared__ ull cand[NB];   // 4 KB
  __shared__ ull swin[8];
  __shared__ int s_p;
  const int j = threadIdx.x;
  const float* xr = obj_dists + (size_t)j * NC;

  // ---- phase A: softmax constants + per-row top-8 (stable desc) ----
  float m = xr[0];
  for (int c = 1; c < NC; ++c) m = fmaxf(m, xr[c]);
  float s = 0.f;
  for (int c = 0; c < NC; ++c) s += expf(xr[c] - m);
  float lv[8]; int lc[8];
#pragma unroll
  for (int t = 0; t < 8; ++t) { lv[t] = -3.4e38f; lc[t] = 0; }
  for (int c = 0; c < NC; ++c) {
    float v = (c == 0) ? 0.0f : (expf(xr[c] - m) / s);
    if (v > lv[7]) {
      lv[7] = v; lc[7] = c;
#pragma unroll
      for (int t = 7; t > 0; --t) {
        if (lv[t] > lv[t - 1]) {
          float tv = lv[t]; lv[t] = lv[t - 1]; lv[t - 1] = tv;
          int tc = lc[t]; lc[t] = lc[t - 1]; lc[t - 1] = tc;
        }
      }
    }
  }
  float rowmax = lv[0]; int argcls = lc[0];

  unsigned mask[5] = {0, 0, 0, 0, 0};
  bool retired = false;
  int post_min = INT_MAX;     // min class resurrected (set to 0) after retirement
  int commitcls = 0;
  int committed = 0;

  while (committed < NB) {
    cand[j] = packkey(rowmax, j * NC + argcls);
    __syncthreads();

    if (j < 64) {
      // gather 512 candidates, 8 per lane (stride-64: 2-way banks, conflict-free)
      ull vloc[8];
#pragma unroll
      for (int t = 0; t < 8; ++t) vloc[t] = cand[j + 64 * t];
      ull lmax = vloc[0];
#pragma unroll
      for (int t = 1; t < 8; ++t) lmax = (vloc[t] > lmax) ? vloc[t] : lmax;

      ull wk[8];
      int kmax = NB - committed; if (kmax > 8) kmax = 8;
      bool stop = false;
      for (int t = 0; t < 8; ++t) {
        if (t >= kmax || stop) { wk[t] = 0; continue; }
        ull g = lmax;
#pragma unroll
        for (int d = 1; d < 64; d <<= 1) {
          ull o = __shfl_xor(g, d, 64);
          g = (o > g) ? o : g;
        }
        wk[t] = g;
        if (lmax == g) {         // unique winner lane: pop and rescan local 8
#pragma unroll
          for (int u = 0; u < 8; ++u) if (vloc[u] == g) vloc[u] = 0;
          lmax = vloc[0];
#pragma unroll
          for (int u = 1; u < 8; ++u) lmax = (vloc[u] > lmax) ? vloc[u] : lmax;
        }
        if (!key_pos(g)) stop = true;  // value <= 0: nothing beyond can chain
      }

      // pairwise chain-suppression: lane (t,s) = (j>>3, j&7) handles pair s<t
      int myt = j >> 3, mys = j & 7;
      ull kT = wk[0], kS = wk[0];
#pragma unroll
      for (int t = 1; t < 8; ++t) { kT = (myt == t) ? wk[t] : kT; kS = (mys == t) ? wk[t] : kS; }
      bool sup = false;
      if (mys < myt && kT != 0 && kS != 0) {
        int it = key_idx(kT), is = key_idx(kS);
        int rt = it / NC, ct = it - rt * NC;
        int rs = is / NC, cs = is - rs * NC;
        (void)rt; (void)rs;
        if (ct == cs) {
          float4 bs = *(const float4*)(boxes + (size_t)is * 4);  // earlier commit = "committed" slot
          float4 bt = *(const float4*)(boxes + (size_t)it * 4);
          sup = overlap_ge(bs, bt);
        }
      }
      ull B = __ballot(sup);     // bit (8*t + s)
      unsigned validset = 1; int p = 1;
#pragma unroll
      for (int t = 1; t < 8; ++t) {
        if (p == t) {
          bool ok = (wk[t] != 0) && key_pos(wk[t]) && (((B >> (8 * t)) & (ull)validset) == 0);
          if (ok) { validset |= (1u << t); p = t + 1; }
        }
      }
      if (j == 0) s_p = p;
#pragma unroll
      for (int t = 0; t < 8; ++t) if (j == t) swin[t] = wk[t];
    }
    __syncthreads();

    // ---- all threads: apply the p commits in order ----
    int p = s_p;
    ull w[8];
#pragma unroll
    for (int t = 0; t < 8; ++t) w[t] = swin[t];
    int rows_[8], clss_[8];
#pragma unroll
    for (int t = 0; t < 8; ++t) {
      int idx = key_idx(w[t]); int r = idx / NC;
      rows_[t] = r; clss_[t] = idx - r * NC;
    }
    float4 cb[8], ob[8];
#pragma unroll
    for (int t = 0; t < 8; ++t) if (t < p) {
      cb[t] = *(const float4*)(boxes + (size_t)(rows_[t] * NC + clss_[t]) * 4);
      ob[t] = *(const float4*)(boxes + (size_t)(j * NC + clss_[t]) * 4);
    }
#pragma unroll
    for (int t = 0; t < 8; ++t) if (t < p) {
      if (j == rows_[t]) {
        // commit: col update is overwritten by row := -1 (reference order)
        retired = true; commitcls = clss_[t]; post_min = INT_MAX;
      } else if (overlap_ge(cb[t], ob[t])) {
        if (retired) {
          post_min = min(post_min, clss_[t]);   // resurrect -1 -> 0.0
        } else {
          int c = clss_[t];
#pragma unroll
          for (int k = 0; k < 5; ++k) if (k == (c >> 5)) mask[k] |= (1u << (c & 31));
        }
      }
    }

    // ---- recompute my candidate ----
    if (retired) {
      rowmax = (post_min != INT_MAX) ? 0.0f : -1.0f;
      argcls = (post_min != INT_MAX) ? post_min : 0;
    } else {
      bool found = false;
#pragma unroll
      for (int t = 0; t < 8; ++t) {
        if (!found) {
          float v = lv[t]; int c = lc[t];
          if (v > 0.0f && !mbit(mask, c)) { rowmax = v; argcls = c; found = true; }
        }
      }
      if (!found) {
        // exact full rescan (bitwise-identical prob recompute)
        float bm = -3.4e38f; int ba = 0;
        for (int c = 0; c < NC; ++c) {
          float v;
          if (c == 0) v = 0.0f;
          else v = mbit(mask, c) ? 0.0f : (expf(xr[c] - m) / s);
          if (v > bm) { bm = v; ba = c; }
        }
        rowmax = bm; argcls = ba;
      }
    }
    committed += p;
  }

  commits[j] = (float)commitcls;
}

extern "C" void kernel_launch(void* const* d_in, const int* in_sizes, int n_in,
                              void* d_out, int out_size, void* d_ws, size_t ws_size,
                              hipStream_t stream) {
  const float* A     = (const float*)d_in[0];   // obj_fmap [512,4096]
  const float* boxes = (const float*)d_in[1];   // boxes_per_cls [512,151,4]
  const float* W     = (const float*)d_in[2];   // [4096,151]
  const float* bias  = (const float*)d_in[3];   // [151]
  float* out = (float*)d_out;                   // [512*151] obj_dists ++ [512] commits

  if (ws_size >= (size_t)KS * NB * NC * 4) {
    float* part = (float*)d_ws;
    gemm_partial<<<dim3(NB / 4, KS), 192, 0, stream>>>(A, W, part);
    gemm_reduce<<<(NB * NC + 255) / 256, 256, 0, stream>>>(part, bias, out);
  } else {
    gemm_full<<<NB / 4, 192, 0, stream>>>(A, W, bias, out);
  }
  decode_kernel<<<1, NB, 0, stream>>>(out, boxes, out + NB * NC);
}

// Round 3
// 623.183 us; speedup vs baseline: 2.2306x; 1.1340x over previous
//
#include <hip/hip_runtime.h>
#include <limits.h>

#pragma clang fp contract(off)

#define NB 512
#define NC 151
#define KDIM 4096
#define KS 8
#define KCH (KDIM/KS)   // 512
#define RB 16           // rows per gemm block
#define NMS_TH 0.3f

typedef unsigned long long ull;

// ---------------- DPP wave64 reductions (VALU-latency cross-lane) ----------------
template <int CTRL>
__device__ __forceinline__ int dpp_i(int identity, int x) {
  return __builtin_amdgcn_update_dpp(identity, x, CTRL, 0xF, 0xF, false);
}
__device__ __forceinline__ float wave_max_bcast(float x) {
  const int ID = __float_as_int(-3.4e38f);
  x = fmaxf(x, __int_as_float(dpp_i<0x111>(ID, __float_as_int(x))));  // row_shr:1
  x = fmaxf(x, __int_as_float(dpp_i<0x112>(ID, __float_as_int(x))));  // row_shr:2
  x = fmaxf(x, __int_as_float(dpp_i<0x114>(ID, __float_as_int(x))));  // row_shr:4
  x = fmaxf(x, __int_as_float(dpp_i<0x118>(ID, __float_as_int(x))));  // row_shr:8
  x = fmaxf(x, __int_as_float(dpp_i<0x142>(ID, __float_as_int(x))));  // row_bcast:15
  x = fmaxf(x, __int_as_float(dpp_i<0x143>(ID, __float_as_int(x))));  // row_bcast:31
  return __int_as_float(__builtin_amdgcn_readlane(__float_as_int(x), 63));
}
__device__ __forceinline__ int wave_min_bcast_i(int x) {
  x = (x < dpp_i<0x111>(INT_MAX, x)) ? x : dpp_i<0x111>(INT_MAX, x);
  x = (x < dpp_i<0x112>(INT_MAX, x)) ? x : dpp_i<0x112>(INT_MAX, x);
  x = (x < dpp_i<0x114>(INT_MAX, x)) ? x : dpp_i<0x114>(INT_MAX, x);
  x = (x < dpp_i<0x118>(INT_MAX, x)) ? x : dpp_i<0x118>(INT_MAX, x);
  x = (x < dpp_i<0x142>(INT_MAX, x)) ? x : dpp_i<0x142>(INT_MAX, x);
  x = (x < dpp_i<0x143>(INT_MAX, x)) ? x : dpp_i<0x143>(INT_MAX, x);
  return __builtin_amdgcn_readlane(x, 63);
}

// exact same IoU arithmetic/order as the reference (fp contract off file-wide)
__device__ __forceinline__ bool overlap_ge(const float4& c, const float4& o) {
  float areaC = (c.z - c.x + 1.0f) * (c.w - c.y + 1.0f);
  float areaJ = (o.z - o.x + 1.0f) * (o.w - o.y + 1.0f);
  float iw = fminf(c.z, o.z) - fmaxf(c.x, o.x) + 1.0f;
  float ih = fminf(c.w, o.w) - fmaxf(c.y, o.y) + 1.0f;
  iw = fmaxf(iw, 0.0f); ih = fmaxf(ih, 0.0f);
  float inter = iw * ih;
  float uni = areaC + areaJ - inter;
  return inter / uni >= NMS_TH;
}

__device__ __forceinline__ bool mbit(const unsigned m[5], int c) {
  bool r = false;
#pragma unroll
  for (int k = 0; k < 5; ++k) r = (k == (c >> 5)) ? (((m[k] >> (c & 31)) & 1u) != 0) : r;
  return r;
}

// ---------------- GEMM: split-K partials, 16 rows/block ----------------
__global__ __launch_bounds__(192) void gemm_partial(
    const float* __restrict__ A, const float* __restrict__ W, float* __restrict__ part)
{
  __shared__ float sA[RB * KCH];  // 32 KB
  int rb = blockIdx.x, ks = blockIdx.y;
  const float* Ab = A + (size_t)rb * RB * KDIM + (size_t)ks * KCH;
  for (int i = threadIdx.x; i < RB * (KCH / 4); i += 192) {
    int r = i >> 7;            // KCH/4 = 128
    int k4 = i & 127;
    *(float4*)(sA + r * KCH + k4 * 4) = *(const float4*)(Ab + (size_t)r * KDIM + k4 * 4);
  }
  __syncthreads();
  int c = threadIdx.x;
  if (c < NC) {
    const float* wp = W + (size_t)ks * KCH * NC + c;
    float acc[RB];
#pragma unroll
    for (int r = 0; r < RB; ++r) acc[r] = 0.f;
    for (int k4 = 0; k4 < KCH / 4; ++k4) {
      float w0 = wp[(size_t)(4 * k4 + 0) * NC];
      float w1 = wp[(size_t)(4 * k4 + 1) * NC];
      float w2 = wp[(size_t)(4 * k4 + 2) * NC];
      float w3 = wp[(size_t)(4 * k4 + 3) * NC];
#pragma unroll
      for (int r = 0; r < RB; ++r) {
        float4 a = *(const float4*)(sA + r * KCH + k4 * 4);  // broadcast, conflict-free
        acc[r] = fmaf(a.x, w0, acc[r]);
        acc[r] = fmaf(a.y, w1, acc[r]);
        acc[r] = fmaf(a.z, w2, acc[r]);
        acc[r] = fmaf(a.w, w3, acc[r]);
      }
    }
    float* o = part + (size_t)ks * NB * NC + (size_t)rb * RB * NC + c;
#pragma unroll
    for (int r = 0; r < RB; ++r) o[(size_t)r * NC] = acc[r];
  }
}

__global__ void gemm_reduce(const float* __restrict__ part, const float* __restrict__ bias,
                            float* __restrict__ out) {
  int i = blockIdx.x * 256 + threadIdx.x;
  if (i >= NB * NC) return;
  float acc = 0.f;
#pragma unroll
  for (int ks = 0; ks < KS; ++ks) acc += part[(size_t)ks * NB * NC + i];
  out[i] = acc + bias[i - (i / NC) * NC];
}

// fallback (ws too small)
__global__ __launch_bounds__(192) void gemm_full(
    const float* __restrict__ A, const float* __restrict__ W,
    const float* __restrict__ bias, float* __restrict__ out)
{
  int c = threadIdx.x;
  int r0 = blockIdx.x * 4;
  if (c >= NC) return;
  const float* a = A + (size_t)r0 * KDIM;
  const float* wp = W + c;
  float a0 = 0.f, a1 = 0.f, a2 = 0.f, a3 = 0.f;
#pragma unroll 8
  for (int k = 0; k < KDIM; ++k) {
    float w = wp[(size_t)k * NC];
    a0 = fmaf(a[k],            w, a0);
    a1 = fmaf(a[k + KDIM],     w, a1);
    a2 = fmaf(a[k + 2 * KDIM], w, a2);
    a3 = fmaf(a[k + 3 * KDIM], w, a3);
  }
  float bb = bias[c];
  out[(size_t)(r0 + 0) * NC + c] = a0 + bb;
  out[(size_t)(r0 + 1) * NC + c] = a1 + bb;
  out[(size_t)(r0 + 2) * NC + c] = a2 + bb;
  out[(size_t)(r0 + 3) * NC + c] = a3 + bb;
}

// ---------------- Multi-commit greedy NMS decode ----------------
// One block, 512 threads. Per round (ONE barrier, double-buffered candidates):
// every wave redundantly extracts the exact global top-8 via DPP reductions,
// validates the commit chain, and applies the valid prefix.
__global__ __launch_bounds__(512) void decode_kernel(
    const float* __restrict__ obj_dists, const float* __restrict__ boxes,
    float* __restrict__ commits)
{
  __shared__ ull cand[2][NB];   // 8 KB, double-buffered
  const int j = threadIdx.x;
  const int lane = j & 63;
  const float* xr = obj_dists + (size_t)j * NC;

  // ---- phase A: softmax constants + per-row top-8 (stable desc) ----
  float m = xr[0];
  for (int c = 1; c < NC; ++c) m = fmaxf(m, xr[c]);
  float s = 0.f;
  for (int c = 0; c < NC; ++c) s += expf(xr[c] - m);
  float lv[8]; int lc[8];
#pragma unroll
  for (int t = 0; t < 8; ++t) { lv[t] = -3.4e38f; lc[t] = 0; }
  for (int c = 0; c < NC; ++c) {
    float v = (c == 0) ? 0.0f : (expf(xr[c] - m) / s);
    if (v > lv[7]) {
      lv[7] = v; lc[7] = c;
#pragma unroll
      for (int t = 7; t > 0; --t) {
        if (lv[t] > lv[t - 1]) {
          float tv = lv[t]; lv[t] = lv[t - 1]; lv[t - 1] = tv;
          int tc = lc[t]; lc[t] = lc[t - 1]; lc[t - 1] = tc;
        }
      }
    }
  }
  float rowmax = lv[0]; int argcls = lc[0];

  unsigned mask[5] = {0, 0, 0, 0, 0};
  bool retired = false;
  int post_min = INT_MAX;
  int commitcls = 0;
  int committed = 0;
  int par = 0;

  while (committed < NB) {
    cand[par][j] = ((ull)(unsigned)__float_as_int(rowmax) << 32) | (unsigned)(j * NC + argcls);
    __syncthreads();

    // gather all 512 candidates (identical in every wave)
    float vv[8]; int vi[8];
#pragma unroll
    for (int t = 0; t < 8; ++t) {
      ull k = cand[par][lane + 64 * t];
      vv[t] = __int_as_float((int)(k >> 32));
      vi[t] = (int)(unsigned)(k & 0xFFFFFFFFu);
    }
    float lmv = vv[0]; int lmi = vi[0];
#pragma unroll
    for (int t = 1; t < 8; ++t) if (vv[t] > lmv) { lmv = vv[t]; lmi = vi[t]; }

    // ---- exact top-8 extraction via DPP ----
    float wv[8]; int wi[8];
    int kmax = NB - committed; if (kmax > 8) kmax = 8;
    bool stop = false;
#pragma unroll
    for (int t = 0; t < 8; ++t) {
      if (t >= kmax || stop) { wi[t] = -1; wv[t] = -1.f; continue; }
      float gv = wave_max_bcast(lmv);
      ull tied = __ballot(lmv == gv);
      int gi;
      if (__popcll(tied) == 1) {
        gi = __builtin_amdgcn_readlane(lmi, (int)__ffsll(tied) - 1);
      } else {
        gi = wave_min_bcast_i((lmv == gv) ? lmi : INT_MAX);  // exact min-flat-idx tie-break
      }
      wv[t] = gv; wi[t] = gi;
      if (lmi == gi) {   // winner lane pops and rescans its 8
#pragma unroll
        for (int u = 0; u < 8; ++u) if (vi[u] == gi) vv[u] = -3.0e38f;
        lmv = vv[0]; lmi = vi[0];
#pragma unroll
        for (int u = 1; u < 8; ++u) if (vv[u] > lmv) { lmv = vv[u]; lmi = vi[u]; }
      }
      if (!(gv > 0.0f)) stop = true;   // value <= 0: nothing beyond can chain
    }

    // decode rows/classes (wave-uniform scalars)
    int rows8[8], cls8[8]; unsigned okm = 0;
#pragma unroll
    for (int t = 0; t < 8; ++t) {
      int idx = (wi[t] < 0) ? 0 : wi[t];
      int r = idx / NC;
      rows8[t] = r; cls8[t] = idx - r * NC;
      if (wi[t] >= 0 && wv[t] > 0.f) okm |= (1u << t);
    }

    // ---- pairwise chain validity: lane (t,s) = (lane>>3, lane&7), s<t ----
    int lt = lane >> 3, ls = lane & 7;
    int iT = wi[0], iS = wi[0], cT = cls8[0], cS = cls8[0];
#pragma unroll
    for (int t = 1; t < 8; ++t) {
      iT = (lt == t) ? wi[t]   : iT;  cT = (lt == t) ? cls8[t] : cT;
      iS = (ls == t) ? wi[t]   : iS;  cS = (ls == t) ? cls8[t] : cS;
    }
    bool sup = false;
    if (ls < lt && ((okm >> lt) & 1) && ((okm >> ls) & 1) && cT == cS && iT >= 0 && iS >= 0) {
      float4 bs = *(const float4*)(boxes + (size_t)iS * 4);  // earlier commit
      float4 bt = *(const float4*)(boxes + (size_t)iT * 4);
      sup = overlap_ge(bs, bt);
    }
    ull B = __ballot(sup);   // bit (8*t + s); identical in every wave
    unsigned validset = 1; int p = 1;
#pragma unroll
    for (int t = 1; t < 8; ++t) {
      if (p == t && ((okm >> t) & 1) && (((B >> (8 * t)) & (ull)validset) == 0)) {
        validset |= (1u << t); p = t + 1;
      }
    }

    // ---- all threads: apply the p commits in order ----
    float4 cb[8], ob[8];
#pragma unroll
    for (int t = 0; t < 8; ++t) if (t < p) {
      cb[t] = *(const float4*)(boxes + (size_t)wi[t] * 4);                 // uniform -> s_load
      ob[t] = *(const float4*)(boxes + ((size_t)j * NC + cls8[t]) * 4);
    }
#pragma unroll
    for (int t = 0; t < 8; ++t) if (t < p) {
      if (j == rows8[t]) {
        // commit: col update overwritten by row := -1 (reference order)
        retired = true; commitcls = cls8[t]; post_min = INT_MAX;
      } else if (overlap_ge(cb[t], ob[t])) {
        if (retired) {
          post_min = (cls8[t] < post_min) ? cls8[t] : post_min;  // resurrect -1 -> 0.0
        } else {
          int c = cls8[t];
#pragma unroll
          for (int k5 = 0; k5 < 5; ++k5) if (k5 == (c >> 5)) mask[k5] |= (1u << (c & 31));
        }
      }
    }

    // ---- recompute my candidate ----
    if (retired) {
      rowmax = (post_min != INT_MAX) ? 0.0f : -1.0f;
      argcls = (post_min != INT_MAX) ? post_min : 0;
    } else {
      bool found = false;
#pragma unroll
      for (int t = 0; t < 8; ++t) {
        if (!found) {
          float v = lv[t]; int c = lc[t];
          if (v > 0.0f && !mbit(mask, c)) { rowmax = v; argcls = c; found = true; }
        }
      }
      if (!found) {
        // exact full rescan (bitwise-identical prob recompute)
        float bm = -3.4e38f; int ba = 0;
        for (int c = 0; c < NC; ++c) {
          float v;
          if (c == 0) v = 0.0f;
          else v = mbit(mask, c) ? 0.0f : (expf(xr[c] - m) / s);
          if (v > bm) { bm = v; ba = c; }
        }
        rowmax = bm; argcls = ba;
      }
    }
    committed += p;
    par ^= 1;
  }

  commits[j] = (float)commitcls;
}

extern "C" void kernel_launch(void* const* d_in, const int* in_sizes, int n_in,
                              void* d_out, int out_size, void* d_ws, size_t ws_size,
                              hipStream_t stream) {
  const float* A     = (const float*)d_in[0];   // obj_fmap [512,4096]
  const float* boxes = (const float*)d_in[1];   // boxes_per_cls [512,151,4]
  const float* W     = (const float*)d_in[2];   // [4096,151]
  const float* bias  = (const float*)d_in[3];   // [151]
  float* out = (float*)d_out;                   // [512*151] obj_dists ++ [512] commits

  if (ws_size >= (size_t)KS * NB * NC * 4) {
    float* part = (float*)d_ws;
    gemm_partial<<<dim3(NB / RB, KS), 192, 0, stream>>>(A, W, part);
    gemm_reduce<<<(NB * NC + 255) / 256, 256, 0, stream>>>(part, bias, out);
  } else {
    gemm_full<<<NB / 4, 192, 0, stream>>>(A, W, bias, out);
  }
  decode_kernel<<<1, NB, 0, stream>>>(out, boxes, out + NB * NC);
}